// Round 15
// baseline (385.247 us; speedup 1.0000x reference)
//
#include <hip/hip_runtime.h>

typedef __attribute__((ext_vector_type(4))) float f32x4;
typedef __attribute__((ext_vector_type(8))) __bf16 bf16x8;

constexpr int FD = 128;   // feature dim D = H = 128

typedef __attribute__((address_space(3))) unsigned int* lds_u32p;
typedef const __attribute__((address_space(1))) unsigned int* gbl_u32p;

__device__ __forceinline__ uint4 pack8(const float* v) {
  union { __bf16 h[8]; uint4 u; } cv;
#pragma unroll
  for (int q = 0; q < 8; ++q) cv.h[q] = (__bf16)v[q];
  return cv.u;
}
__device__ __forceinline__ unsigned int pack2(float a, float b) {
  union { __bf16 h[2]; unsigned int u; } cv;
  cv.h[0] = (__bf16)a; cv.h[1] = (__bf16)b;
  return cv.u;
}

// node_x f32 -> bf16 table (halves random-gather bytes in the edge kernel)
__global__ void cvt_bf16(const float* __restrict__ x, unsigned short* __restrict__ o, int n8) {
  int i = blockIdx.x * 256 + threadIdx.x;
  if (i >= n8) return;
  const float* p = x + (size_t)i * 8;
  float v[8];
#pragma unroll
  for (int q = 0; q < 8; ++q) v[q] = p[q];
  *(uint4*)(o + (size_t)i * 8) = pack8(v);
}

// Pack a (K,128) f32 weight matrix into 16x16x32 MFMA B-fragment order, bf16:
// dst[((nt*KS + ks)*64 + lane)*8 + e] = W[k][n]
__global__ void pack_weights(const float* __restrict__ mw0, const float* __restrict__ mw1,
                             const float* __restrict__ mw2, const float* __restrict__ uw0,
                             const float* __restrict__ uw1, const float* __restrict__ uw2,
                             unsigned short* __restrict__ wp) {
  int tid = blockIdx.x * 256 + threadIdx.x;   // 576*256 == 147456 exactly
  const float* src; int base, K;
  if      (tid < 49152)  { src = mw0; base = 0;      K = 384; }
  else if (tid < 65536)  { src = mw1; base = 49152;  K = 128; }
  else if (tid < 81920)  { src = mw2; base = 65536;  K = 128; }
  else if (tid < 114688) { src = uw0; base = 81920;  K = 256; }
  else if (tid < 131072) { src = uw1; base = 114688; K = 128; }
  else                   { src = uw2; base = 131072; K = 128; }
  int i = tid - base;
  int k = i >> 7, n = i & 127;
  int KS = K >> 5;
  int dst = base + (((n >> 4) * KS + (k >> 5)) * 64 + ((k >> 3) & 3) * 16 + (n & 15)) * 8 + (k & 7);
  union { __bf16 h; unsigned short s; } cv; cv.h = (__bf16)src[i];
  wp[dst] = cv.s;
}

// Fragment-order LDS layout (R7/R14, validated). Tiles (8192 shorts each):
//   t0 = x_dst -> C1, t1 = x_src -> C0 -> h2, t2 = edge_attr.
// t0 is dead after the h2-pub barrier -> next tile's x_dst DMA prefetch target.

template<bool RELU>
__device__ __forceinline__ void store_frag(unsigned short* sDst, const f32x4* acc, float bias) {
#pragma unroll
  for (int m = 0; m < 4; ++m)
#pragma unroll
    for (int ri = 0; ri < 4; ++ri) {
      float v = acc[m][ri] + bias;
      if (RELU) v = fmaxf(v, 0.f);
      union { __bf16 h; unsigned short s; } cv; cv.h = (__bf16)v;
      sDst[m * 512 + ri * 32] = cv.s;
    }
}

// Edge kernel: PERSISTENT blocks (grid = 3/CU), each loops over 64-edge tiles.
// Next tile's x-gather DMA + ea staging overlap current tile's epilogue.
__global__ __launch_bounds__(512, 6)
void in_edge_kernel(const float* __restrict__ node_x, const unsigned short* __restrict__ nxbf,
                    const float* __restrict__ edge_attr,
                    const int* __restrict__ eidx, const unsigned short* __restrict__ wp,
                    const float* __restrict__ b0p, const float* __restrict__ b1p,
                    const float* __restrict__ b2p, const float* __restrict__ gp,
                    const float* __restrict__ bep,
                    unsigned short* __restrict__ msg, int* __restrict__ head,
                    int* __restrict__ nxt, float* __restrict__ agg,
                    int use_sort, int E) {
  __shared__ unsigned short sBuf[3072 * 8];   // 48KB frag-order buffer
  __shared__ int sSrc[2][64], sDst[2][64];
  __shared__ float sG[128], sB[128];

  const int t = threadIdx.x;
  const int lane = t & 63, w = t >> 6;
  const int ln = lane & 15, g16 = lane >> 4;
  const int rdoff = ln * 32 + g16 * 8;
  const int stoff = (w >> 1) * 2048 + g16 * 128
                  + (((2 * w) + (ln >> 3)) & 3) * 8 + (ln & 7);
  const int eStart = blockIdx.x * 64;
  const int stride = gridDim.x * 64;

  // B pools: b0 6-deep ring (reloaded per tile), B1r persistent across tiles.
  bf16x8 b0[6], B1r[4];
#pragma unroll
  for (int ks = 0; ks < 6; ++ks)
    b0[ks] = *(const bf16x8*)(wp + (size_t)((w * 12 + ks) * 64 + lane) * 8);
#pragma unroll
  for (int ks = 0; ks < 4; ++ks)
    B1r[ks] = *(const bf16x8*)(wp + 49152 + (size_t)((w * 4 + ks) * 64 + lane) * 8);

  // params + idx(tile 0)
  if (t < 64) {
    sSrc[0][t] = (eStart + t < E) ? eidx[eStart + t] : 0;
  } else if (t < 128) {
    int r = t - 64;
    int e = eStart + r;
    int d = (e < E) ? eidx[E + e] : 0;
    sDst[0][r] = d;
    if (use_sort && e < E) nxt[e] = atomicExch(&head[d], e);
  } else if (t < 256) {
    sG[t - 128] = gp[t - 128];
  } else if (t < 384) {
    sB[t - 256] = bep[t - 256];
  }
  __syncthreads();

  // ---- stage tile 0 ----
  if (eStart < E) {
    if (nxbf) {
#pragma unroll
      for (int i = 0; i < 4; ++i) {
        int g = w * 4 + i;                     // 0..31
        int tile = g >> 4;                     // 0: x_dst->t0, 1: x_src->t1
        int ks = (g >> 2) & 3, m = g & 3;
        int row = m * 16 + (lane >> 2);
        int idx = tile ? sSrc[0][row] : sDst[0][row];
        const unsigned short* gp2 = nxbf + (size_t)idx * FD + ks * 32 + (lane & 3) * 8;
        lds_u32p lp = (lds_u32p)&sBuf[tile * 8192 + (size_t)(ks * 4 + m) * 512];
        __builtin_amdgcn_global_load_lds((gbl_u32p)gp2, lp, 16, 0, 0);
      }
    } else {
#pragma unroll
      for (int it = 0; it < 16; ++it) {
        const int type = it >> 3;
        int row = ((it & 7) << 3) + w;
        float2 v = {0.f, 0.f};
        if (eStart + row < E) {
          const float* sp = (type == 0) ? node_x + (size_t)sDst[0][row] * FD
                                        : node_x + (size_t)sSrc[0][row] * FD;
          v = *(const float2*)(sp + lane * 2);
        }
        int c = (((type * 4 + (lane >> 4)) * 4 + (row >> 4)) * 64
                 + (row & 15) * 4 + ((lane >> 2) & 3)) * 8 + (lane & 3) * 2;
        *(unsigned int*)&sBuf[c] = pack2(v.x, v.y);
      }
    }
#pragma unroll
    for (int it = 0; it < 8; ++it) {           // edge_attr -> t2
      int row = it * 8 + w;
      float2 v = {0.f, 0.f};
      if (eStart + row < E) v = *(const float2*)(edge_attr + (size_t)(eStart + row) * FD + lane * 2);
      int c = 16384 + (((lane >> 4) * 4 + (row >> 4)) * 64
                       + (row & 15) * 4 + ((lane >> 2) & 3)) * 8 + (lane & 3) * 2;
      *(unsigned int*)&sBuf[c] = pack2(v.x, v.y);
    }
  }

  const int col = w * 16 + ln;
  const float b0v = b0p[col], b1v = b1p[col], b2v = b2p[col];

  int cb = 0;
  for (int e0 = eStart; e0 < E; e0 += stride, cb ^= 1) {
    const bool hasNext = nxbf && (e0 + stride < E);
    __syncthreads();                              // staging-pub (drains DMA)

    f32x4 acc[4];
#pragma unroll
    for (int m = 0; m < 4; ++m) acc[m] = (f32x4){0.f, 0.f, 0.f, 0.f};

    // ---- layer 0: K=384, pipelined B ----
#pragma unroll
    for (int ks = 0; ks < 12; ++ks) {
      bf16x8 bb = b0[ks % 6];
      if (ks + 6 < 12)
        b0[ks % 6] = *(const bf16x8*)(wp + (size_t)((w * 12 + ks + 6) * 64 + lane) * 8);
#pragma unroll
      for (int m = 0; m < 4; ++m) {
        bf16x8 a = *(const bf16x8*)&sBuf[(ks * 4 + m) * 512 + rdoff];
        acc[m] = __builtin_amdgcn_mfma_f32_16x16x32_bf16(a, bb, acc[m], 0, 0, 0);
      }
    }
    bf16x8 B2r[4];
#pragma unroll
    for (int ks = 0; ks < 4; ++ks)
      B2r[ks] = *(const bf16x8*)(wp + 65536 + (size_t)((w * 4 + ks) * 64 + lane) * 8);

    __syncthreads();                              // L0-end
    store_frag<true>(sBuf + 8192 + stoff, acc, b0v);   // C0 -> t1 (x_src dead)
    if (hasNext) {                                // idx(next) load + list build
      int eN = e0 + stride;
      if (t < 64) {
        sSrc[cb ^ 1][t] = (eN + t < E) ? eidx[eN + t] : 0;
      } else if (t < 128) {
        int r = t - 64;
        int e = eN + r;
        int d = (e < E) ? eidx[E + e] : 0;
        sDst[cb ^ 1][r] = d;
        if (use_sort && e < E) nxt[e] = atomicExch(&head[d], e);
      }
    }
    __syncthreads();                              // C0-pub + idx-pub

    // ---- layer 1 ----
#pragma unroll
    for (int m = 0; m < 4; ++m) acc[m] = (f32x4){0.f, 0.f, 0.f, 0.f};
#pragma unroll
    for (int ks = 0; ks < 4; ++ks)
#pragma unroll
      for (int m = 0; m < 4; ++m) {
        bf16x8 a = *(const bf16x8*)&sBuf[8192 + (ks * 4 + m) * 512 + rdoff];
        acc[m] = __builtin_amdgcn_mfma_f32_16x16x32_bf16(a, B1r[ks], acc[m], 0, 0, 0);
      }
    store_frag<true>(sBuf + stoff, acc, b1v);     // C1 -> t0 (x_dst dead)
    __syncthreads();                              // C1-pub

    // ---- layer 2 ----
#pragma unroll
    for (int m = 0; m < 4; ++m) acc[m] = (f32x4){0.f, 0.f, 0.f, 0.f};
#pragma unroll
    for (int ks = 0; ks < 4; ++ks)
#pragma unroll
      for (int m = 0; m < 4; ++m) {
        bf16x8 a = *(const bf16x8*)&sBuf[(ks * 4 + m) * 512 + rdoff];
        acc[m] = __builtin_amdgcn_mfma_f32_16x16x32_bf16(a, B2r[ks], acc[m], 0, 0, 0);
      }
    store_frag<false>(sBuf + 8192 + stoff, acc, b2v);  // h2 -> t1 (C0 dead)
    __syncthreads();                              // h2-pub; t0 fully dead

    if (hasNext) {                                // prefetch x_dst(next) -> t0 (DMA)
#pragma unroll
      for (int i = 0; i < 2; ++i) {
        int g = w * 2 + i;                        // 0..15
        int ks = g >> 2, m = g & 3;
        int row = m * 16 + (lane >> 2);
        int idx = sDst[cb ^ 1][row];
        const unsigned short* gp2 = nxbf + (size_t)idx * FD + ks * 32 + (lane & 3) * 8;
        lds_u32p lp = (lds_u32p)&sBuf[(size_t)(ks * 4 + m) * 512];
        __builtin_amdgcn_global_load_lds((gbl_u32p)gp2, lp, 16, 0, 0);
      }
    }

    // ---- fused LN stats + epilogue, row-wise (8 threads per row) ----
    {
      int row = t >> 3, j = t & 7;
      int a0 = (((j >> 1) * 4 + (row >> 4)) * 64 + (row & 15) * 4 + 2 * (j & 1)) * 8;
      bf16x8 v0 = *(const bf16x8*)&sBuf[8192 + a0];
      bf16x8 v1 = *(const bf16x8*)&sBuf[8192 + a0 + 8];
      float s1 = 0.f, s2 = 0.f;
#pragma unroll
      for (int q = 0; q < 8; ++q) {
        float a = (float)v0[q], b = (float)v1[q];
        s1 += a + b; s2 += a * a + b * b;
      }
#pragma unroll
      for (int m = 1; m < 8; m <<= 1) {
        s1 += __shfl_xor(s1, m, 64);
        s2 += __shfl_xor(s2, m, 64);
      }
      float mean = s1 * (1.f / 128.f);
      float var  = s2 * (1.f / 128.f) - mean * mean;
      float rstd = rsqrtf(fmaxf(var, 0.f) + 1e-5f);

      int e = e0 + row;
      if (e < E) {
        bf16x8 ea0 = *(const bf16x8*)&sBuf[16384 + a0];
        bf16x8 ea1 = *(const bf16x8*)&sBuf[16384 + a0 + 8];
        float val[16];
#pragma unroll
        for (int q = 0; q < 8; ++q) {
          val[q]     = ((float)v0[q] - mean) * rstd * sG[j * 16 + q]     + sB[j * 16 + q]     + (float)ea0[q];
          val[8 + q] = ((float)v1[q] - mean) * rstd * sG[j * 16 + 8 + q] + sB[j * 16 + 8 + q] + (float)ea1[q];
        }
        if (use_sort) {
          uint4* dst = (uint4*)(msg + (size_t)e * FD + j * 16);
          dst[0] = pack8(val);
          dst[1] = pack8(val + 8);
        } else {
          float* ap = agg + (size_t)sDst[cb][row] * FD + j * 16;
#pragma unroll
          for (int q = 0; q < 16; ++q) atomicAdd(ap + q, val[q]);
        }
      }
    }

    if (hasNext) {                                // reload b0 ring for next tile
#pragma unroll
      for (int ks = 0; ks < 6; ++ks)
        b0[ks] = *(const bf16x8*)(wp + (size_t)((w * 12 + ks) * 64 + lane) * 8);
    }
    __syncthreads();                              // epilogue-end; t1,t2 dead

    if (hasNext) {
      // x_src(next) -> t1 (DMA)
#pragma unroll
      for (int i = 0; i < 2; ++i) {
        int g = w * 2 + i;
        int ks = g >> 2, m = g & 3;
        int row = m * 16 + (lane >> 2);
        int idx = sSrc[cb ^ 1][row];
        const unsigned short* gp2 = nxbf + (size_t)idx * FD + ks * 32 + (lane & 3) * 8;
        lds_u32p lp = (lds_u32p)&sBuf[8192 + (size_t)(ks * 4 + m) * 512];
        __builtin_amdgcn_global_load_lds((gbl_u32p)gp2, lp, 16, 0, 0);
      }
      // ea(next) -> t2
      int eN = e0 + stride;
#pragma unroll
      for (int it = 0; it < 8; ++it) {
        int row = it * 8 + w;
        float2 v = {0.f, 0.f};
        if (eN + row < E) v = *(const float2*)(edge_attr + (size_t)(eN + row) * FD + lane * 2);
        int c = 16384 + (((lane >> 4) * 4 + (row >> 4)) * 64
                         + (row & 15) * 4 + ((lane >> 2) & 3)) * 8 + (lane & 3) * 2;
        *(unsigned int*)&sBuf[c] = pack2(v.x, v.y);
      }
    }
  }
}

// Node kernel: 64 nodes/block (R14 verbatim).
__global__ __launch_bounds__(512, 8)
void in_node_kernel(const float* __restrict__ node_x, const unsigned short* __restrict__ nxbf,
                    const unsigned short* __restrict__ msg, const int* __restrict__ head,
                    const int* __restrict__ nxt, const float* __restrict__ agg,
                    const unsigned short* __restrict__ wp,
                    const float* __restrict__ b0p, const float* __restrict__ b1p,
                    const float* __restrict__ b2p, const float* __restrict__ gp,
                    const float* __restrict__ bep, float* __restrict__ out,
                    int use_sort, int N) {
  __shared__ unsigned short sBuf[2048 * 8];
  __shared__ float sG[128], sB[128];

  const int t = threadIdx.x;
  const int r0 = blockIdx.x * 64;
  const int lane = t & 63, w = t >> 6;
  const int ln = lane & 15, g16 = lane >> 4;
  const int col = w * 16 + ln;
  const int rdoff = ln * 32 + g16 * 8;
  const int stoff = (w >> 1) * 2048 + g16 * 128
                  + (((2 * w) + (ln >> 3)) & 3) * 8 + (ln & 7);

  bf16x8 b0[4];
#pragma unroll
  for (int ks = 0; ks < 4; ++ks)
    b0[ks] = *(const bf16x8*)(wp + 81920 + (size_t)((w * 8 + ks) * 64 + lane) * 8);

  if (t < 128)      sG[t] = gp[t];
  else if (t < 256) sB[t - 128] = bep[t - 128];

  if (nxbf) {
#pragma unroll
    for (int i = 0; i < 2; ++i) {
      int g = w * 2 + i;
      int ks = g >> 2, m = g & 3;
      int row = m * 16 + (lane >> 2);
      const unsigned short* gp2 = nxbf + (size_t)(r0 + row) * FD + ks * 32 + (lane & 3) * 8;
      lds_u32p lp = (lds_u32p)&sBuf[(size_t)(ks * 4 + m) * 512];
      __builtin_amdgcn_global_load_lds((gbl_u32p)gp2, lp, 16, 0, 0);
    }
  } else {
#pragma unroll
    for (int it = 0; it < 8; ++it) {
      int row = (it << 3) + w;
      int r = r0 + row;
      float2 v = {0.f, 0.f};
      if (r < N) v = *(const float2*)(node_x + (size_t)r * FD + lane * 2);
      int c = (((lane >> 4) * 4 + (row >> 4)) * 64
               + (row & 15) * 4 + ((lane >> 2) & 3)) * 8 + (lane & 3) * 2;
      *(unsigned int*)&sBuf[c] = pack2(v.x, v.y);
    }
  }

  {
    int row = t >> 3, j = t & 7;
    int node = r0 + row;
    float a[16];
#pragma unroll
    for (int q = 0; q < 16; ++q) a[q] = 0.f;
    if (node < N) {
      if (use_sort) {
        int e = head[node];
        while (e >= 0) {
          int ne = nxt[e];
          bf16x8 m0 = *(const bf16x8*)(msg + (size_t)e * FD + j * 16);
          bf16x8 m1 = *(const bf16x8*)(msg + (size_t)e * FD + j * 16 + 8);
#pragma unroll
          for (int q = 0; q < 8; ++q) { a[q] += (float)m0[q]; a[8 + q] += (float)m1[q]; }
          e = ne;
        }
      } else {
        const float* ap = agg + (size_t)node * FD + j * 16;
#pragma unroll
        for (int q4 = 0; q4 < 4; ++q4) {
          f32x4 u = *(const f32x4*)(ap + q4 * 4);
#pragma unroll
          for (int q = 0; q < 4; ++q) a[q4 * 4 + q] = u[q];
        }
      }
    }
    int c = 8192 + (((j >> 1) * 4 + (row >> 4)) * 64 + (row & 15) * 4 + 2 * (j & 1)) * 8;
    *(uint4*)&sBuf[c] = pack8(a);
    *(uint4*)&sBuf[c + 8] = pack8(a + 8);
  }
  __syncthreads();

  const float b0v = b0p[col], b1v = b1p[col], b2v = b2p[col];

  f32x4 acc[4];
#pragma unroll
  for (int m = 0; m < 4; ++m) acc[m] = (f32x4){0.f, 0.f, 0.f, 0.f};

#pragma unroll
  for (int ks = 0; ks < 8; ++ks) {
    bf16x8 bb = b0[ks % 4];
    if (ks + 4 < 8)
      b0[ks % 4] = *(const bf16x8*)(wp + 81920 + (size_t)((w * 8 + ks + 4) * 64 + lane) * 8);
#pragma unroll
    for (int m = 0; m < 4; ++m) {
      bf16x8 a = *(const bf16x8*)&sBuf[(ks * 4 + m) * 512 + rdoff];
      acc[m] = __builtin_amdgcn_mfma_f32_16x16x32_bf16(a, bb, acc[m], 0, 0, 0);
    }
  }
  bf16x8 B1r[4];
#pragma unroll
  for (int ks = 0; ks < 4; ++ks)
    B1r[ks] = *(const bf16x8*)(wp + 114688 + (size_t)((w * 4 + ks) * 64 + lane) * 8);

  __syncthreads();
  store_frag<true>(sBuf + stoff, acc, b0v);
  __syncthreads();

#pragma unroll
  for (int m = 0; m < 4; ++m) acc[m] = (f32x4){0.f, 0.f, 0.f, 0.f};
#pragma unroll
  for (int ks = 0; ks < 4; ++ks)
#pragma unroll
    for (int m = 0; m < 4; ++m) {
      bf16x8 a = *(const bf16x8*)&sBuf[(ks * 4 + m) * 512 + rdoff];
      acc[m] = __builtin_amdgcn_mfma_f32_16x16x32_bf16(a, B1r[ks], acc[m], 0, 0, 0);
    }
  bf16x8 B2r[4];
#pragma unroll
  for (int ks = 0; ks < 4; ++ks)
    B2r[ks] = *(const bf16x8*)(wp + 131072 + (size_t)((w * 4 + ks) * 64 + lane) * 8);
  store_frag<true>(sBuf + 8192 + stoff, acc, b1v);
  __syncthreads();

#pragma unroll
  for (int m = 0; m < 4; ++m) acc[m] = (f32x4){0.f, 0.f, 0.f, 0.f};
#pragma unroll
  for (int ks = 0; ks < 4; ++ks)
#pragma unroll
    for (int m = 0; m < 4; ++m) {
      bf16x8 a = *(const bf16x8*)&sBuf[8192 + (ks * 4 + m) * 512 + rdoff];
      acc[m] = __builtin_amdgcn_mfma_f32_16x16x32_bf16(a, B2r[ks], acc[m], 0, 0, 0);
    }
  store_frag<false>(sBuf + stoff, acc, b2v);
  __syncthreads();

  {
    int row = t >> 3, j = t & 7;
    int a0 = (((j >> 1) * 4 + (row >> 4)) * 64 + (row & 15) * 4 + 2 * (j & 1)) * 8;
    bf16x8 v0 = *(const bf16x8*)&sBuf[a0];
    bf16x8 v1 = *(const bf16x8*)&sBuf[a0 + 8];
    float s1 = 0.f, s2 = 0.f;
#pragma unroll
    for (int q = 0; q < 8; ++q) {
      float a = (float)v0[q], b = (float)v1[q];
      s1 += a + b; s2 += a * a + b * b;
    }
#pragma unroll
    for (int m = 1; m < 8; m <<= 1) {
      s1 += __shfl_xor(s1, m, 64);
      s2 += __shfl_xor(s2, m, 64);
    }
    float mean = s1 * (1.f / 128.f);
    float var  = s2 * (1.f / 128.f) - mean * mean;
    float rstd = rsqrtf(fmaxf(var, 0.f) + 1e-5f);

    int node = r0 + row;
    if (node < N) {
      float o[16];
#pragma unroll
      for (int q = 0; q < 8; ++q) {
        o[q]     = ((float)v0[q] - mean) * rstd * sG[j * 16 + q]     + sB[j * 16 + q];
        o[8 + q] = ((float)v1[q] - mean) * rstd * sG[j * 16 + 8 + q] + sB[j * 16 + 8 + q];
      }
      const float* xr = node_x + (size_t)node * FD + j * 16;
      float* orow = out + (size_t)node * FD + j * 16;
#pragma unroll
      for (int q4 = 0; q4 < 4; ++q4) {
        f32x4 x = *(const f32x4*)(xr + q4 * 4);
        f32x4 wv;
#pragma unroll
        for (int q = 0; q < 4; ++q) wv[q] = o[q4 * 4 + q] + x[q];
        *(f32x4*)(orow + q4 * 4) = wv;
      }
    }
  }
}

extern "C" void kernel_launch(void* const* d_in, const int* in_sizes, int n_in,
                              void* d_out, int out_size, void* d_ws, size_t ws_size,
                              hipStream_t stream) {
  const float* node_x    = (const float*)d_in[0];
  const float* edge_attr = (const float*)d_in[1];
  const int*   eidx      = (const int*)d_in[2];
  const int N = in_sizes[0] / FD;
  const int E = in_sizes[1] / FD;

  char* ws = (char*)d_ws;
  auto aln = [](size_t x) { return (x + 255) & ~(size_t)255; };
  const size_t wpB   = aln(294912);
  const size_t nxbfB = aln((size_t)N * FD * 2 + 16384);   // +pad for tail-block DMA overread
  const size_t headB = aln((size_t)N * 4);
  const size_t nxtB  = aln((size_t)E * 4);
  const size_t msgB  = (size_t)E * FD * 2;

  unsigned short* wp = (unsigned short*)ws;
  unsigned short* nxbf = nullptr;
  int* head = nullptr; int* nxt = nullptr;
  unsigned short* msg = nullptr; float* agg = nullptr;
  int use_sort = 0;

  if (ws_size >= wpB + nxbfB + headB + nxtB + msgB) {          // full: bf16 table + sort
    use_sort = 1;
    nxbf = (unsigned short*)(ws + wpB);
    head = (int*)(ws + wpB + nxbfB);
    nxt  = (int*)(ws + wpB + nxbfB + headB);
    msg  = (unsigned short*)(ws + wpB + nxbfB + headB + nxtB);
  } else if (ws_size >= wpB + headB + nxtB + msgB) {           // sort, no bf16 table
    use_sort = 1;
    head = (int*)(ws + wpB);
    nxt  = (int*)(ws + wpB + headB);
    msg  = (unsigned short*)(ws + wpB + headB + nxtB);
  } else {                                                     // atomic fallback
    agg = (float*)(ws + wpB);
  }

  if (use_sort) (void)hipMemsetAsync(head, 0xFF, (size_t)N * 4, stream);
  else          (void)hipMemsetAsync(agg, 0, (size_t)N * FD * sizeof(float), stream);

  pack_weights<<<576, 256, 0, stream>>>(
      (const float*)d_in[3], (const float*)d_in[5], (const float*)d_in[7],
      (const float*)d_in[11], (const float*)d_in[13], (const float*)d_in[15], wp);
  if (nxbf) cvt_bf16<<<(N * FD / 8 + 255) / 256, 256, 0, stream>>>(node_x, nxbf, N * FD / 8);

  int nt = (E + 63) / 64;
  int egrid = (nxbf && use_sort) ? (nt < 768 ? nt : 768) : nt;   // persistent: 3 blocks/CU
  in_edge_kernel<<<egrid, 512, 0, stream>>>(
      node_x, nxbf, edge_attr, eidx, wp,
      (const float*)d_in[4], (const float*)d_in[6], (const float*)d_in[8],
      (const float*)d_in[9], (const float*)d_in[10],
      msg, head, nxt, agg, use_sort, E);
  in_node_kernel<<<(N + 63) / 64, 512, 0, stream>>>(
      node_x, nxbf, msg, head, nxt, agg, wp,
      (const float*)d_in[12], (const float*)d_in[14], (const float*)d_in[16],
      (const float*)d_in[17], (const float*)d_in[18], (float*)d_out, use_sort, N);
}